// Round 2
// baseline (878.263 us; speedup 1.0000x reference)
//
#include <hip/hip_runtime.h>
#include <hip/hip_bf16.h>
#include <math.h>

// UniMP 2-layer TransformerConv. N=50000, E=800000, G=512, D=64 (edge 16).
// R1: bf16-packed kv gathers (4B/lane/edge), CSR-ordered bf16 edge_attr (no eid
// indirection), register-preloaded csr_src, 4-edge load batching, no online max.

typedef unsigned int uint32;
typedef unsigned short ushort16;

__device__ __forceinline__ uint32 f2bf(float x) {
    uint32 u = __float_as_uint(x);
    u += 0x7fffu + ((u >> 16) & 1u);
    return u >> 16;
}

// ---------------- CSR build ----------------

__global__ void hist_kernel(const int* __restrict__ dst, int* __restrict__ deg, int E) {
    int e = blockIdx.x * blockDim.x + threadIdx.x;
    if (e < E) atomicAdd(&deg[dst[e]], 1);
}

__global__ void scan1_kernel(const int* __restrict__ deg, int* __restrict__ row_ptr,
                             int* __restrict__ totals, int N) {
    __shared__ int sh[1024];
    int tid = threadIdx.x;
    int i = blockIdx.x * 1024 + tid;
    int d = (i < N) ? deg[i] : 0;
    int val = d;
    sh[tid] = val;
    __syncthreads();
    for (int off = 1; off < 1024; off <<= 1) {
        int add = (tid >= off) ? sh[tid - off] : 0;
        __syncthreads();
        val += add;
        sh[tid] = val;
        __syncthreads();
    }
    if (i < N) row_ptr[i] = val - d;
    if (tid == 1023) totals[blockIdx.x] = val;
}

__global__ void scan2_kernel(int* totals, int nb) {
    if (threadIdx.x == 0 && blockIdx.x == 0) {
        int run = 0;
        for (int b = 0; b < nb; ++b) { int t = totals[b]; totals[b] = run; run += t; }
    }
}

__global__ void scan3_kernel(int* __restrict__ row_ptr, const int* __restrict__ totals,
                             int N, int E) {
    int i = blockIdx.x * blockDim.x + threadIdx.x;
    if (i < N) row_ptr[i] += totals[i >> 10];
    if (i == 0) row_ptr[N] = E;
}

// scatter + edge_attr -> bf16 in CSR order
__global__ void scatter_kernel(const int* __restrict__ src, const int* __restrict__ dst,
                               const int* __restrict__ row_ptr, int* __restrict__ fill,
                               const float* __restrict__ ea,
                               int* __restrict__ csr_src, ushort16* __restrict__ ea16, int E) {
    int e = blockIdx.x * blockDim.x + threadIdx.x;
    if (e >= E) return;
    int d = dst[e];
    int pos = row_ptr[d] + atomicAdd(&fill[d], 1);
    csr_src[pos] = src[e];
    const float4* ev = (const float4*)(ea + (size_t)e * 16);
    float4 q0 = ev[0], q1 = ev[1], q2 = ev[2], q3 = ev[3];
    uint32* d32 = (uint32*)(ea16 + (size_t)pos * 16);
    d32[0] = f2bf(q0.x) | (f2bf(q0.y) << 16);
    d32[1] = f2bf(q0.z) | (f2bf(q0.w) << 16);
    d32[2] = f2bf(q1.x) | (f2bf(q1.y) << 16);
    d32[3] = f2bf(q1.z) | (f2bf(q1.w) << 16);
    d32[4] = f2bf(q2.x) | (f2bf(q2.y) << 16);
    d32[5] = f2bf(q2.z) | (f2bf(q2.w) << 16);
    d32[6] = f2bf(q3.x) | (f2bf(q3.y) << 16);
    d32[7] = f2bf(q3.z) | (f2bf(q3.w) << 16);
}

// ---------------- fused node linears ----------------
// blockIdx.y: 0 -> q (fp32), 1 -> k&v packed bf16, 2 -> skip (fp32)

__global__ __launch_bounds__(256) void qkvs_kernel(
    const float* __restrict__ xin,
    const float* __restrict__ wqm, const float* __restrict__ bqm,
    const float* __restrict__ wkm, const float* __restrict__ bkm,
    const float* __restrict__ wvm, const float* __restrict__ bvm,
    const float* __restrict__ wsm, const float* __restrict__ bsm,
    float* __restrict__ qo, uint32* __restrict__ kvo,
    float* __restrict__ so, int N)
{
    int mtx = blockIdx.y;
    __shared__ float W0[64][64];
    __shared__ float W1[64][64];
    __shared__ float X[64][64];
    int t = threadIdx.x;
    int col = t & 63;
    int sub = t >> 6;

    const float* w0 = (mtx == 0) ? wqm : (mtx == 1) ? wkm : wsm;
    const float* b0p = (mtx == 0) ? bqm : (mtx == 1) ? bkm : bsm;
    for (int r = t; r < 4096; r += 256) W0[r >> 6][r & 63] = w0[r];
    if (mtx == 1)
        for (int r = t; r < 4096; r += 256) W1[r >> 6][r & 63] = wvm[r];
    int n0 = blockIdx.x * 64;
    for (int r = t; r < 4096; r += 256) {
        int n = n0 + (r >> 6);
        X[r >> 6][r & 63] = (n < N) ? xin[(size_t)n * 64 + (r & 63)] : 0.f;
    }
    __syncthreads();

    float b0 = b0p[col];
    float b1 = (mtx == 1) ? bvm[col] : 0.f;

    for (int nb = sub * 16; nb < sub * 16 + 16; nb += 8) {
        float a0[8], a1[8];
        #pragma unroll
        for (int u = 0; u < 8; ++u) { a0[u] = b0; a1[u] = b1; }
        if (mtx == 1) {
            for (int j = 0; j < 64; ++j) {
                float wk_ = W0[j][col], wv_ = W1[j][col];
                #pragma unroll
                for (int u = 0; u < 8; ++u) {
                    float xv = X[nb + u][j];
                    a0[u] = fmaf(xv, wk_, a0[u]);
                    a1[u] = fmaf(xv, wv_, a1[u]);
                }
            }
        } else {
            for (int j = 0; j < 64; ++j) {
                float wj = W0[j][col];
                #pragma unroll
                for (int u = 0; u < 8; ++u) a0[u] = fmaf(X[nb + u][j], wj, a0[u]);
            }
        }
        #pragma unroll
        for (int u = 0; u < 8; ++u) {
            int n = n0 + nb + u;
            if (n < N) {
                if (mtx == 0)      qo[(size_t)n * 64 + col] = a0[u];
                else if (mtx == 2) so[(size_t)n * 64 + col] = a0[u];
                else kvo[(size_t)n * 64 + col] = f2bf(a0[u]) | (f2bf(a1[u]) << 16);
            }
        }
    }
}

// ---------------- per-node softmax aggregation ----------------
// One wave per node, lane = feature. bf16 kv packed; ea16 in CSR order.

__global__ __launch_bounds__(256) void agg_kernel(
    const float* __restrict__ q, const uint32* __restrict__ kv,
    const float* __restrict__ we, const ushort16* __restrict__ ea16,
    const int* __restrict__ row_ptr, const int* __restrict__ csr_src,
    const float* __restrict__ skip_in, float* __restrict__ hout, int N, int E16)
{
    int wid = (blockIdx.x * blockDim.x + threadIdx.x) >> 6;
    int lane = threadIdx.x & 63;
    if (wid >= N) return;

    float wer[16];
    #pragma unroll
    for (int j = 0; j < 16; ++j) wer[j] = we[j * 64 + lane];
    float ql = q[(size_t)wid * 64 + lane] * 0.125f;   // fold 1/sqrt(64)

    float den = 0.f, o = 0.f;
    int beg = row_ptr[wid], end = row_ptr[wid + 1];

    for (int c = beg; c < end; c += 64) {
        int cN = end - c; if (cN > 64) cN = 64;
        int sp = csr_src[(c + lane < end) ? (c + lane) : (end - 1)];
        for (int p = 0; p < cN; p += 4) {
            // preload ea for 4 edges: 64 bf16 across the wave
            float eav;
            {
                int ei = (c + p) * 16 + lane;
                eav = (ei < E16) ? __uint_as_float(((uint32)ea16[0 * 0 + 0], 0u)) : 0.f; // placeholder (replaced below)
            }
            {
                int ei = (c + p) * 16 + lane;
                ushort16 raw = (ei < E16) ? ((const ushort16*)ea16)[ei] : (ushort16)0;
                eav = __uint_as_float(((uint32)raw) << 16);
            }
            int s[4];
            #pragma unroll
            for (int u = 0; u < 4; ++u) s[u] = __shfl(sp, (p + u < cN) ? (p + u) : p);
            uint32 kb[4];
            #pragma unroll
            for (int u = 0; u < 4; ++u) kb[u] = kv[(size_t)s[u] * 64 + lane];
            #pragma unroll
            for (int u = 0; u < 4; ++u) {
                float kl = __uint_as_float((kb[u] & 0xffffu) << 16);
                float vl = __uint_as_float(kb[u] & 0xffff0000u);
                float ee = 0.f;
                #pragma unroll
                for (int j = 0; j < 16; ++j) ee = fmaf(__shfl(eav, u * 16 + j), wer[j], ee);
                float sc = ql * (kl + ee);
                #pragma unroll
                for (int off = 32; off; off >>= 1) sc += __shfl_xor(sc, off);
                float w = __expf(sc);
                if (p + u < cN) { den += w; o = fmaf(w, vl + ee, o); }
            }
        }
    }
    float dinv = (den > 0.f) ? 1.f / den : 0.f;
    float r = o * dinv + skip_in[(size_t)wid * 64 + lane];
    hout[(size_t)wid * 64 + lane] = (r >= 0.f) ? r : 0.01f * r;
}

// ---------------- pooling (run-length, batch sorted) + head ----------------

__global__ void pool_kernel(const float* __restrict__ atom, const int* __restrict__ batch,
                            float* __restrict__ pooled, int N) {
    int w = (blockIdx.x * blockDim.x + threadIdx.x) >> 6;
    int lane = threadIdx.x & 63;
    int n0 = w * 8;
    if (n0 >= N) return;
    int nend = n0 + 8; if (nend > N) nend = N;
    int cur = batch[n0];
    float acc = 0.f;
    for (int n = n0; n < nend; ++n) {
        int b = batch[n];
        if (b != cur) {
            atomicAdd(&pooled[cur * 64 + lane], acc);
            acc = 0.f; cur = b;
        }
        acc += atom[(size_t)n * 64 + lane];
    }
    atomicAdd(&pooled[cur * 64 + lane], acc);
}

__global__ void head_kernel(const float* __restrict__ pooled,
                            const float* __restrict__ w1, const float* __restrict__ b1,
                            const float* __restrict__ w2, const float* __restrict__ b2,
                            float* __restrict__ out, int G) {
    int g = blockIdx.x;
    int lane = threadIdx.x;
    __shared__ float hl[64];
    float p = pooled[g * 64 + lane];
    float ss = p * p;
    #pragma unroll
    for (int off = 32; off; off >>= 1) ss += __shfl_xor(ss, off);
    float hn = p / fmaxf(sqrtf(ss), 1e-12f);
    hl[lane] = hn;
    __syncthreads();
    float acc = b1[lane];
    #pragma unroll
    for (int j = 0; j < 64; ++j) acc = fmaf(hl[j], w1[j * 64 + lane], acc);
    acc = (acc >= 0.f) ? acc : 0.01f * acc;
    float r = acc * w2[lane];
    #pragma unroll
    for (int off = 32; off; off >>= 1) r += __shfl_xor(r, off);
    if (lane == 0) out[g] = r + b2[0];
}

// ---------------- launch ----------------

extern "C" void kernel_launch(void* const* d_in, const int* in_sizes, int n_in,
                              void* d_out, int out_size, void* d_ws, size_t ws_size,
                              hipStream_t stream) {
    const float* x     = (const float*)d_in[0];
    const int*   ei    = (const int*)  d_in[1];
    const float* ea    = (const float*)d_in[2];
    const int*   batch = (const int*)  d_in[3];
    const float *wq1=(const float*)d_in[4],  *bq1=(const float*)d_in[5];
    const float *wk1=(const float*)d_in[6],  *bk1=(const float*)d_in[7];
    const float *wv1=(const float*)d_in[8],  *bv1=(const float*)d_in[9];
    const float *we1=(const float*)d_in[10];
    const float *ws1=(const float*)d_in[11], *bs1=(const float*)d_in[12];
    const float *wq2=(const float*)d_in[13], *bq2=(const float*)d_in[14];
    const float *wk2=(const float*)d_in[15], *bk2=(const float*)d_in[16];
    const float *wv2=(const float*)d_in[17], *bv2=(const float*)d_in[18];
    const float *we2=(const float*)d_in[19];
    const float *ws2=(const float*)d_in[20], *bs2=(const float*)d_in[21];
    const float *wf1=(const float*)d_in[22], *bf1=(const float*)d_in[23];
    const float *wf2=(const float*)d_in[24], *bf2=(const float*)d_in[25];

    int N = in_sizes[0] / 64;
    int E = in_sizes[2] / 16;
    int G = out_size - N * 64;

    const int* srcA = ei;
    const int* dstA = ei + E;

    char* w = (char*)d_ws;
    float*  qb      = (float*)w;  w += (size_t)N * 64 * 4;
    uint32* kvb     = (uint32*)w; w += (size_t)N * 64 * 4;
    float*  hb      = (float*)w;  w += (size_t)N * 64 * 4;
    float*  pooled  = (float*)w;  w += (size_t)G * 64 * 4;
    int* row_ptr    = (int*)w;    w += (size_t)(N + 1) * 4;
    int* deg        = (int*)w;    w += (size_t)N * 4;
    int* fill       = (int*)w;    w += (size_t)N * 4;
    int* totals     = (int*)w;    w += 256 * 4;
    int* csr_src    = (int*)w;    w += (size_t)E * 4;
    ushort16* ea16  = (ushort16*)w; w += (size_t)E * 16 * 2;

    hipMemsetAsync(deg, 0, (size_t)N * 4, stream);
    hipMemsetAsync(fill, 0, (size_t)N * 4, stream);
    hipMemsetAsync(pooled, 0, (size_t)G * 64 * 4, stream);

    const int TB = 256;
    hist_kernel<<<(E + TB - 1) / TB, TB, 0, stream>>>(dstA, deg, E);
    int nb = (N + 1023) / 1024;
    scan1_kernel<<<nb, 1024, 0, stream>>>(deg, row_ptr, totals, N);
    scan2_kernel<<<1, 64, 0, stream>>>(totals, nb);
    scan3_kernel<<<(N + TB - 1) / TB, TB, 0, stream>>>(row_ptr, totals, N, E);
    scatter_kernel<<<(E + TB - 1) / TB, TB, 0, stream>>>(srcA, dstA, row_ptr, fill, ea,
                                                         csr_src, ea16, E);

    float* outp = (float*)d_out;
    float* atom = outp + G;

    dim3 qgrid((N + 63) / 64, 3);
    int aggBlocks = (N * 64 + TB - 1) / TB;

    qkvs_kernel<<<qgrid, 256, 0, stream>>>(x, wq1, bq1, wk1, bk1, wv1, bv1, ws1, bs1,
                                           qb, kvb, hb, N);
    agg_kernel<<<aggBlocks, TB, 0, stream>>>(qb, kvb, we1, ea16, row_ptr, csr_src,
                                             hb, hb, N, E * 16);

    qkvs_kernel<<<qgrid, 256, 0, stream>>>(hb, wq2, bq2, wk2, bk2, wv2, bv2, ws2, bs2,
                                           qb, kvb, atom, N);
    agg_kernel<<<aggBlocks, TB, 0, stream>>>(qb, kvb, we2, ea16, row_ptr, csr_src,
                                             atom, atom, N, E * 16);

    pool_kernel<<<((N + 7) / 8 * 64 + TB - 1) / TB, TB, 0, stream>>>(atom, batch, pooled, N);
    head_kernel<<<G, 64, 0, stream>>>(pooled, wf1, bf1, wf2, bf2, outp, G);
}

// Round 3
// 517.798 us; speedup vs baseline: 1.6961x; 1.6961x over previous
//
#include <hip/hip_runtime.h>
#include <hip/hip_bf16.h>
#include <math.h>

// UniMP 2-layer TransformerConv. N=50000, E=800000, G=512, D=64 (edge 16).
// R3: one 64-thread block per node -> all edge-loop addresses wave-uniform ->
// compiler emits s_load (SMEM pipe) for csr_src/csr_eid/edge_attr; edge-MLP is
// 16 scalar-operand v_fma (no shuffles). Only 6 shfl_xor/edge remain (score).

typedef unsigned int uint32;

__device__ __forceinline__ uint32 f2bf(float x) {
    uint32 u = __float_as_uint(x);
    u += 0x7fffu + ((u >> 16) & 1u);
    return u >> 16;
}

// ---------------- CSR build ----------------

__global__ void hist_kernel(const int* __restrict__ dst, int* __restrict__ deg, int E) {
    int e = blockIdx.x * blockDim.x + threadIdx.x;
    if (e < E) atomicAdd(&deg[dst[e]], 1);
}

__global__ void scan1_kernel(const int* __restrict__ deg, int* __restrict__ row_ptr,
                             int* __restrict__ totals, int N) {
    __shared__ int sh[1024];
    int tid = threadIdx.x;
    int i = blockIdx.x * 1024 + tid;
    int d = (i < N) ? deg[i] : 0;
    int val = d;
    sh[tid] = val;
    __syncthreads();
    for (int off = 1; off < 1024; off <<= 1) {
        int add = (tid >= off) ? sh[tid - off] : 0;
        __syncthreads();
        val += add;
        sh[tid] = val;
        __syncthreads();
    }
    if (i < N) row_ptr[i] = val - d;
    if (tid == 1023) totals[blockIdx.x] = val;
}

__global__ void scan2_kernel(int* totals, int nb) {
    if (threadIdx.x == 0 && blockIdx.x == 0) {
        int run = 0;
        for (int b = 0; b < nb; ++b) { int t = totals[b]; totals[b] = run; run += t; }
    }
}

__global__ void scan3_kernel(int* __restrict__ row_ptr, const int* __restrict__ totals,
                             int N, int E) {
    int i = blockIdx.x * blockDim.x + threadIdx.x;
    if (i < N) row_ptr[i] += totals[i >> 10];
    if (i == 0) row_ptr[N] = E;
}

__global__ void scatter_kernel(const int* __restrict__ src, const int* __restrict__ dst,
                               const int* __restrict__ row_ptr, int* __restrict__ fill,
                               int* __restrict__ csr_src, int* __restrict__ csr_eid, int E) {
    int e = blockIdx.x * blockDim.x + threadIdx.x;
    if (e < E) {
        int d = dst[e];
        int pos = row_ptr[d] + atomicAdd(&fill[d], 1);
        csr_src[pos] = src[e];
        csr_eid[pos] = e;
    }
}

// ---------------- fused node linears ----------------
// blockIdx.y: 0 -> q (fp32), 1 -> k&v packed bf16, 2 -> skip (fp32)

__global__ __launch_bounds__(256) void qkvs_kernel(
    const float* __restrict__ xin,
    const float* __restrict__ wqm, const float* __restrict__ bqm,
    const float* __restrict__ wkm, const float* __restrict__ bkm,
    const float* __restrict__ wvm, const float* __restrict__ bvm,
    const float* __restrict__ wsm, const float* __restrict__ bsm,
    float* __restrict__ qo, uint32* __restrict__ kvo,
    float* __restrict__ so, int N)
{
    int mtx = blockIdx.y;
    __shared__ float W0[64][64];
    __shared__ float W1[64][64];
    __shared__ float X[64][64];
    int t = threadIdx.x;
    int col = t & 63;
    int sub = t >> 6;

    const float* w0 = (mtx == 0) ? wqm : (mtx == 1) ? wkm : wsm;
    const float* b0p = (mtx == 0) ? bqm : (mtx == 1) ? bkm : bsm;
    for (int r = t; r < 4096; r += 256) W0[r >> 6][r & 63] = w0[r];
    if (mtx == 1)
        for (int r = t; r < 4096; r += 256) W1[r >> 6][r & 63] = wvm[r];
    int n0 = blockIdx.x * 64;
    for (int r = t; r < 4096; r += 256) {
        int n = n0 + (r >> 6);
        X[r >> 6][r & 63] = (n < N) ? xin[(size_t)n * 64 + (r & 63)] : 0.f;
    }
    __syncthreads();

    float b0 = b0p[col];
    float b1 = (mtx == 1) ? bvm[col] : 0.f;

    for (int nb = sub * 16; nb < sub * 16 + 16; nb += 8) {
        float a0[8], a1[8];
        #pragma unroll
        for (int u = 0; u < 8; ++u) { a0[u] = b0; a1[u] = b1; }
        if (mtx == 1) {
            for (int j = 0; j < 64; ++j) {
                float wk_ = W0[j][col], wv_ = W1[j][col];
                #pragma unroll
                for (int u = 0; u < 8; ++u) {
                    float xv = X[nb + u][j];
                    a0[u] = fmaf(xv, wk_, a0[u]);
                    a1[u] = fmaf(xv, wv_, a1[u]);
                }
            }
        } else {
            for (int j = 0; j < 64; ++j) {
                float wj = W0[j][col];
                #pragma unroll
                for (int u = 0; u < 8; ++u) a0[u] = fmaf(X[nb + u][j], wj, a0[u]);
            }
        }
        #pragma unroll
        for (int u = 0; u < 8; ++u) {
            int n = n0 + nb + u;
            if (n < N) {
                if (mtx == 0)      qo[(size_t)n * 64 + col] = a0[u];
                else if (mtx == 2) so[(size_t)n * 64 + col] = a0[u];
                else kvo[(size_t)n * 64 + col] = f2bf(a0[u]) | (f2bf(a1[u]) << 16);
            }
        }
    }
}

// ---------------- per-node softmax aggregation ----------------
// One 64-thread block (one wave) per node; lane = feature dim.
// All edge-loop scalars (p, csr_src[p], csr_eid[p], edge_attr row) are
// wave-uniform -> scalar loads. kv packed bf16 gathered per lane.

__device__ __forceinline__ void edge_acc(uint32 kb, const float* __restrict__ eap,
                                         const float* wer, float ql,
                                         float& den, float& o) {
    float kl = __uint_as_float((kb & 0xffffu) << 16);
    float vl = __uint_as_float(kb & 0xffff0000u);
    float sea[16];
    #pragma unroll
    for (int j = 0; j < 16; ++j) sea[j] = eap[j];
    float ee = 0.f;
    #pragma unroll
    for (int j = 0; j < 16; ++j) ee = fmaf(sea[j], wer[j], ee);
    float sc = ql * (kl + ee);
    #pragma unroll
    for (int off = 32; off; off >>= 1) sc += __shfl_xor(sc, off);
    float w = __expf(sc);
    den += w;
    o = fmaf(w, vl + ee, o);
}

__global__ __launch_bounds__(64) void agg_kernel(
    const float* __restrict__ q, const uint32* __restrict__ kv,
    const float* __restrict__ we, const float* __restrict__ ea,
    const int* __restrict__ row_ptr, const int* __restrict__ csr_src,
    const int* __restrict__ csr_eid,
    const float* __restrict__ skip_in, float* __restrict__ hout, int N)
{
    int i = blockIdx.x;
    int lane = threadIdx.x;

    float wer[16];
    #pragma unroll
    for (int j = 0; j < 16; ++j) wer[j] = we[j * 64 + lane];
    float ql = q[(size_t)i * 64 + lane] * 0.125f;   // fold 1/sqrt(64)

    float den = 0.f, o = 0.f;
    int beg = row_ptr[i], end = row_ptr[i + 1];

    int p = beg;
    for (; p + 4 <= end; p += 4) {
        int s0 = csr_src[p], s1 = csr_src[p + 1], s2 = csr_src[p + 2], s3 = csr_src[p + 3];
        int e0 = csr_eid[p], e1 = csr_eid[p + 1], e2 = csr_eid[p + 2], e3 = csr_eid[p + 3];
        uint32 kb0 = kv[(size_t)s0 * 64 + lane];
        uint32 kb1 = kv[(size_t)s1 * 64 + lane];
        uint32 kb2 = kv[(size_t)s2 * 64 + lane];
        uint32 kb3 = kv[(size_t)s3 * 64 + lane];
        edge_acc(kb0, ea + (size_t)e0 * 16, wer, ql, den, o);
        edge_acc(kb1, ea + (size_t)e1 * 16, wer, ql, den, o);
        edge_acc(kb2, ea + (size_t)e2 * 16, wer, ql, den, o);
        edge_acc(kb3, ea + (size_t)e3 * 16, wer, ql, den, o);
    }
    for (; p < end; ++p) {
        int s = csr_src[p];
        int e = csr_eid[p];
        uint32 kb = kv[(size_t)s * 64 + lane];
        edge_acc(kb, ea + (size_t)e * 16, wer, ql, den, o);
    }

    float dinv = (den > 0.f) ? 1.f / den : 0.f;
    float r = o * dinv + skip_in[(size_t)i * 64 + lane];
    hout[(size_t)i * 64 + lane] = (r >= 0.f) ? r : 0.01f * r;
}

// ---------------- pooling (run-length, batch sorted) + head ----------------

__global__ void pool_kernel(const float* __restrict__ atom, const int* __restrict__ batch,
                            float* __restrict__ pooled, int N) {
    int w = (blockIdx.x * blockDim.x + threadIdx.x) >> 6;
    int lane = threadIdx.x & 63;
    int n0 = w * 8;
    if (n0 >= N) return;
    int nend = n0 + 8; if (nend > N) nend = N;
    int cur = batch[n0];
    float acc = 0.f;
    for (int n = n0; n < nend; ++n) {
        int b = batch[n];
        if (b != cur) {
            atomicAdd(&pooled[cur * 64 + lane], acc);
            acc = 0.f; cur = b;
        }
        acc += atom[(size_t)n * 64 + lane];
    }
    atomicAdd(&pooled[cur * 64 + lane], acc);
}

__global__ void head_kernel(const float* __restrict__ pooled,
                            const float* __restrict__ w1, const float* __restrict__ b1,
                            const float* __restrict__ w2, const float* __restrict__ b2,
                            float* __restrict__ out, int G) {
    int g = blockIdx.x;
    int lane = threadIdx.x;
    __shared__ float hl[64];
    float p = pooled[g * 64 + lane];
    float ss = p * p;
    #pragma unroll
    for (int off = 32; off; off >>= 1) ss += __shfl_xor(ss, off);
    float hn = p / fmaxf(sqrtf(ss), 1e-12f);
    hl[lane] = hn;
    __syncthreads();
    float acc = b1[lane];
    #pragma unroll
    for (int j = 0; j < 64; ++j) acc = fmaf(hl[j], w1[j * 64 + lane], acc);
    acc = (acc >= 0.f) ? acc : 0.01f * acc;
    float r = acc * w2[lane];
    #pragma unroll
    for (int off = 32; off; off >>= 1) r += __shfl_xor(r, off);
    if (lane == 0) out[g] = r + b2[0];
}

// ---------------- launch ----------------

extern "C" void kernel_launch(void* const* d_in, const int* in_sizes, int n_in,
                              void* d_out, int out_size, void* d_ws, size_t ws_size,
                              hipStream_t stream) {
    const float* x     = (const float*)d_in[0];
    const int*   ei    = (const int*)  d_in[1];
    const float* ea    = (const float*)d_in[2];
    const int*   batch = (const int*)  d_in[3];
    const float *wq1=(const float*)d_in[4],  *bq1=(const float*)d_in[5];
    const float *wk1=(const float*)d_in[6],  *bk1=(const float*)d_in[7];
    const float *wv1=(const float*)d_in[8],  *bv1=(const float*)d_in[9];
    const float *we1=(const float*)d_in[10];
    const float *ws1=(const float*)d_in[11], *bs1=(const float*)d_in[12];
    const float *wq2=(const float*)d_in[13], *bq2=(const float*)d_in[14];
    const float *wk2=(const float*)d_in[15], *bk2=(const float*)d_in[16];
    const float *wv2=(const float*)d_in[17], *bv2=(const float*)d_in[18];
    const float *we2=(const float*)d_in[19];
    const float *ws2=(const float*)d_in[20], *bs2=(const float*)d_in[21];
    const float *wf1=(const float*)d_in[22], *bf1=(const float*)d_in[23];
    const float *wf2=(const float*)d_in[24], *bf2=(const float*)d_in[25];

    int N = in_sizes[0] / 64;
    int E = in_sizes[2] / 16;
    int G = out_size - N * 64;

    const int* srcA = ei;
    const int* dstA = ei + E;

    char* w = (char*)d_ws;
    float*  qb      = (float*)w;  w += (size_t)N * 64 * 4;
    uint32* kvb     = (uint32*)w; w += (size_t)N * 64 * 4;
    float*  hb      = (float*)w;  w += (size_t)N * 64 * 4;
    float*  pooled  = (float*)w;  w += (size_t)G * 64 * 4;
    int* row_ptr    = (int*)w;    w += (size_t)(N + 1) * 4;
    int* deg        = (int*)w;    w += (size_t)N * 4;
    int* fill       = (int*)w;    w += (size_t)N * 4;
    int* totals     = (int*)w;    w += 256 * 4;
    int* csr_src    = (int*)w;    w += (size_t)E * 4;
    int* csr_eid    = (int*)w;    w += (size_t)E * 4;

    hipMemsetAsync(deg, 0, (size_t)N * 4, stream);
    hipMemsetAsync(fill, 0, (size_t)N * 4, stream);
    hipMemsetAsync(pooled, 0, (size_t)G * 64 * 4, stream);

    const int TB = 256;
    hist_kernel<<<(E + TB - 1) / TB, TB, 0, stream>>>(dstA, deg, E);
    int nb = (N + 1023) / 1024;
    scan1_kernel<<<nb, 1024, 0, stream>>>(deg, row_ptr, totals, N);
    scan2_kernel<<<1, 64, 0, stream>>>(totals, nb);
    scan3_kernel<<<(N + TB - 1) / TB, TB, 0, stream>>>(row_ptr, totals, N, E);
    scatter_kernel<<<(E + TB - 1) / TB, TB, 0, stream>>>(srcA, dstA, row_ptr, fill,
                                                         csr_src, csr_eid, E);

    float* outp = (float*)d_out;
    float* atom = outp + G;

    dim3 qgrid((N + 63) / 64, 3);

    qkvs_kernel<<<qgrid, 256, 0, stream>>>(x, wq1, bq1, wk1, bk1, wv1, bv1, ws1, bs1,
                                           qb, kvb, hb, N);
    agg_kernel<<<N, 64, 0, stream>>>(qb, kvb, we1, ea, row_ptr, csr_src, csr_eid,
                                     hb, hb, N);

    qkvs_kernel<<<qgrid, 256, 0, stream>>>(hb, wq2, bq2, wk2, bk2, wv2, bv2, ws2, bs2,
                                           qb, kvb, atom, N);
    agg_kernel<<<N, 64, 0, stream>>>(qb, kvb, we2, ea, row_ptr, csr_src, csr_eid,
                                     atom, atom, N);

    pool_kernel<<<((N + 7) / 8 * 64 + TB - 1) / TB, TB, 0, stream>>>(atom, batch, pooled, N);
    head_kernel<<<G, 64, 0, stream>>>(pooled, wf1, bf1, wf2, bf2, outp, G);
}